// Round 1
// baseline (310.595 us; speedup 1.0000x reference)
//
#include <hip/hip_runtime.h>
#include <math.h>

#define Bn 32
#define Cn 256
#define Hn 64
#define Wn 64
#define MIP 8
#define OUP 256
#define BN_EPS 1e-5f

// ---------------------------------------------------------------------------
// Kernel 1: per-(b,c) stats -> A[b][c][s], s in [0,128)
//   s<64:  a_h[h] = rowsum[h]/64 + softmax_h(rowmax)[h]/64
//   s>=64: a_w[w] = colsum[w]/64 + softmax_w(colmax)[w]/64
// ---------------------------------------------------------------------------
__global__ __launch_bounds__(256) void stats_kernel(const float* __restrict__ x,
                                                    float* __restrict__ A) {
    const int bc = blockIdx.x;                       // b*Cn + c
    const float* xp = x + (size_t)bc * (Hn * Wn);
    __shared__ float tile[Hn * 65];                  // pitch 65 -> (h+w)%32 banks
    const int t = threadIdx.x;

    // load 64x64 tile, float4-vectorized, coalesced
#pragma unroll
    for (int k = 0; k < 4; ++k) {
        int i4  = t + 256 * k;                       // float4 index 0..1023
        int idx = i4 * 4;
        int h = idx >> 6;
        int w = idx & 63;
        float4 v = ((const float4*)xp)[i4];
        float* dst = &tile[h * 65 + w];
        dst[0] = v.x; dst[1] = v.y; dst[2] = v.z; dst[3] = v.w;
    }
    __syncthreads();

    float red_max = -INFINITY, red_sum = 0.f;
    if (t < 64) {                                    // wave 0: row stats (fixed h)
        int h = t;
#pragma unroll 8
        for (int w = 0; w < Wn; ++w) {
            float v = tile[h * 65 + w];
            red_max = fmaxf(red_max, v);
            red_sum += v;
        }
    } else if (t < 128) {                            // wave 1: col stats (fixed w)
        int w = t - 64;
#pragma unroll 8
        for (int h = 0; h < Hn; ++h) {
            float v = tile[h * 65 + w];
            red_max = fmaxf(red_max, v);
            red_sum += v;
        }
    }

    if (t < 128) {
        // softmax across the 64 lanes of this wave
        float m = red_max;
#pragma unroll
        for (int off = 32; off > 0; off >>= 1) m = fmaxf(m, __shfl_xor(m, off));
        float e = expf(red_max - m);
        float se = e;
#pragma unroll
        for (int off = 32; off > 0; off >>= 1) se += __shfl_xor(se, off);
        float bias = e / se;
        float a = red_sum * (1.0f / 64.0f) + bias * (1.0f / 64.0f);
        A[(size_t)bc * 128 + t] = a;
    }
}

// ---------------------------------------------------------------------------
// Kernel 2: per-b channel mixing.
//   y[m][s]   = sum_c w1[m][c] * A[b][c][s]       (8x128, K=256)
//   yact      = hswish(y*scale + shift)
//   G[b][o][s]= sigmoid(sum_m W2[o][m]*yact[m][s]) (W2 = wh for s<64, ww else)
// ---------------------------------------------------------------------------
__global__ __launch_bounds__(256) void gates_kernel(const float* __restrict__ A,
                                                    const float* __restrict__ w1,
                                                    const float* __restrict__ bn_gamma,
                                                    const float* __restrict__ bn_beta,
                                                    const float* __restrict__ bn_mean,
                                                    const float* __restrict__ bn_var,
                                                    const float* __restrict__ wh,
                                                    const float* __restrict__ ww,
                                                    float* __restrict__ G) {
    const int b = blockIdx.x;
    const int t = threadIdx.x;
    const int s  = t & 127;
    const int mb = t >> 7;                           // 0 or 1

    const float* Ab = A + (size_t)b * Cn * 128;

    float acc[4] = {0.f, 0.f, 0.f, 0.f};
    for (int c = 0; c < Cn; ++c) {
        float a = Ab[(size_t)c * 128 + s];           // coalesced over s
#pragma unroll
        for (int k = 0; k < 4; ++k)
            acc[k] += w1[(mb + 2 * k) * Cn + c] * a; // wave-uniform load
    }

    __shared__ float yact[MIP][128];
#pragma unroll
    for (int k = 0; k < 4; ++k) {
        int m = mb + 2 * k;
        float sc = bn_gamma[m] * rsqrtf(bn_var[m] + BN_EPS);
        float sh = bn_beta[m] - bn_mean[m] * sc;
        float v = acc[k] * sc + sh;
        v = v * fminf(fmaxf(v + 3.0f, 0.0f), 6.0f) * (1.0f / 6.0f);  // hswish
        yact[m][s] = v;
    }
    __syncthreads();

    float ym[MIP];
#pragma unroll
    for (int m = 0; m < MIP; ++m) ym[m] = yact[m][s];
    const float* w2 = (s < 64) ? wh : ww;            // wave-uniform select

    float* Gb = G + (size_t)b * OUP * 128;
    for (int j = 0; j < 128; ++j) {
        int o = (t >> 7) + 2 * j;
        float g = 0.f;
#pragma unroll
        for (int m = 0; m < MIP; ++m) g += w2[o * MIP + m] * ym[m];
        g = 1.0f / (1.0f + expf(-g));
        Gb[(size_t)o * 128 + s] = g;                 // coalesced over s
    }
}

// ---------------------------------------------------------------------------
// Kernel 3: out[b,c,h,w] = x[b,c,h,w] * g_h[b,c,h] * g_w[b,c,w]
// ---------------------------------------------------------------------------
__global__ __launch_bounds__(256) void apply_kernel(const float* __restrict__ x,
                                                    const float* __restrict__ G,
                                                    float* __restrict__ out) {
    const int bc = blockIdx.x;
    const float* xp = x + (size_t)bc * (Hn * Wn);
    float* op = out + (size_t)bc * (Hn * Wn);
    const float* gp = G + (size_t)bc * 128;

    __shared__ float gs[128];                        // [0,64): g_h, [64,128): g_w
    const int t = threadIdx.x;
    if (t < 128) gs[t] = gp[t];
    __syncthreads();

#pragma unroll
    for (int k = 0; k < 4; ++k) {
        int i4  = t + 256 * k;
        int idx = i4 * 4;
        int h = idx >> 6;
        int w = idx & 63;
        float4 v = ((const float4*)xp)[i4];
        float gh = gs[h];
        v.x *= gh * gs[64 + w + 0];
        v.y *= gh * gs[64 + w + 1];
        v.z *= gh * gs[64 + w + 2];
        v.w *= gh * gs[64 + w + 3];
        ((float4*)op)[i4] = v;
    }
}

extern "C" void kernel_launch(void* const* d_in, const int* in_sizes, int n_in,
                              void* d_out, int out_size, void* d_ws, size_t ws_size,
                              hipStream_t stream) {
    const float* x        = (const float*)d_in[0];
    const float* w1       = (const float*)d_in[1];
    const float* bn_gamma = (const float*)d_in[2];
    const float* bn_beta  = (const float*)d_in[3];
    const float* bn_mean  = (const float*)d_in[4];
    const float* bn_var   = (const float*)d_in[5];
    const float* wh       = (const float*)d_in[6];
    const float* ww       = (const float*)d_in[7];
    float* out = (float*)d_out;

    float* A = (float*)d_ws;                               // Bn*Cn*128 = 4 MiB
    float* G = A + (size_t)Bn * Cn * 128;                  // 4 MiB more

    stats_kernel<<<Bn * Cn, 256, 0, stream>>>(x, A);
    gates_kernel<<<Bn, 256, 0, stream>>>(A, w1, bn_gamma, bn_beta, bn_mean,
                                         bn_var, wh, ww, G);
    apply_kernel<<<Bn * Cn, 256, 0, stream>>>(x, G, out);
}

// Round 2
// 298.352 us; speedup vs baseline: 1.0410x; 1.0410x over previous
//
#include <hip/hip_runtime.h>
#include <math.h>

#define Bn 32
#define Cn 256
#define Hn 64
#define Wn 64
#define MIP 8
#define OUP 256
#define BN_EPS 1e-5f

// ---------------------------------------------------------------------------
// Kernel 1: per-(b,c) stats -> A[b][c][s], s in [0,128)
//   s<64:  a_h[h] = rowsum[h]/64 + softmax_h(rowmax)[h]/64
//   s>=64: a_w[w] = colsum[w]/64 + softmax_w(colmax)[w]/64
// (uses: mean_W(bias_h*bias_w) = bias_h/64 since softmax sums to 1)
// ---------------------------------------------------------------------------
__global__ __launch_bounds__(256) void stats_kernel(const float* __restrict__ x,
                                                    float* __restrict__ A) {
    const int bc = blockIdx.x;                       // b*Cn + c
    const float* xp = x + (size_t)bc * (Hn * Wn);
    __shared__ float tile[Hn * 65];                  // pitch 65: 2-way alias max (free)
    const int t = threadIdx.x;

    // load 64x64 tile, float4-vectorized, coalesced
#pragma unroll
    for (int k = 0; k < 4; ++k) {
        int i4  = t + 256 * k;                       // float4 index 0..1023
        int idx = i4 * 4;
        int h = idx >> 6;
        int w = idx & 63;
        float4 v = ((const float4*)xp)[i4];
        float* dst = &tile[h * 65 + w];
        dst[0] = v.x; dst[1] = v.y; dst[2] = v.z; dst[3] = v.w;
    }
    __syncthreads();

    float red_max = -INFINITY, red_sum = 0.f;
    if (t < 64) {                                    // wave 0: row stats (fixed h)
        int h = t;
#pragma unroll 8
        for (int w = 0; w < Wn; ++w) {
            float v = tile[h * 65 + w];
            red_max = fmaxf(red_max, v);
            red_sum += v;
        }
    } else if (t < 128) {                            // wave 1: col stats (fixed w)
        int w = t - 64;
#pragma unroll 8
        for (int h = 0; h < Hn; ++h) {
            float v = tile[h * 65 + w];
            red_max = fmaxf(red_max, v);
            red_sum += v;
        }
    }

    if (t < 128) {
        // softmax across the 64 lanes of this wave
        float m = red_max;
#pragma unroll
        for (int off = 32; off > 0; off >>= 1) m = fmaxf(m, __shfl_xor(m, off));
        float e = expf(red_max - m);
        float se = e;
#pragma unroll
        for (int off = 32; off > 0; off >>= 1) se += __shfl_xor(se, off);
        float a = (red_sum + e / se) * (1.0f / 64.0f);
        A[(size_t)bc * 128 + t] = a;
    }
}

// ---------------------------------------------------------------------------
// Kernel 2 (tiny): yact[b][m][s] = hswish(BN(sum_c w1[m][c] * A[b][c][s]))
//   256 threads: s = t&127, K=256 split across two halves, LDS combine.
// ---------------------------------------------------------------------------
__global__ __launch_bounds__(256) void ymix_kernel(const float* __restrict__ A,
                                                   const float* __restrict__ w1,
                                                   const float* __restrict__ bn_gamma,
                                                   const float* __restrict__ bn_beta,
                                                   const float* __restrict__ bn_mean,
                                                   const float* __restrict__ bn_var,
                                                   float* __restrict__ yact) {
    const int b = blockIdx.x;
    const int t = threadIdx.x;
    const int s    = t & 127;
    const int half = t >> 7;

    const float* Ab = A + (size_t)b * Cn * 128;

    float acc[MIP];
#pragma unroll
    for (int m = 0; m < MIP; ++m) acc[m] = 0.f;

    const int c0 = half * 128;
    for (int c = c0; c < c0 + 128; ++c) {
        float a = Ab[(size_t)c * 128 + s];           // coalesced over s
#pragma unroll
        for (int m = 0; m < MIP; ++m)
            acc[m] += w1[m * Cn + c] * a;            // wave-uniform scalar load
    }

    __shared__ float red[MIP][128];
    if (half == 1) {
#pragma unroll
        for (int m = 0; m < MIP; ++m) red[m][s] = acc[m];
    }
    __syncthreads();
    if (half == 0) {
#pragma unroll
        for (int m = 0; m < MIP; ++m) {
            float v = acc[m] + red[m][s];
            float sc = bn_gamma[m] * rsqrtf(bn_var[m] + BN_EPS);
            float sh = bn_beta[m] - bn_mean[m] * sc;
            v = v * sc + sh;
            v = v * fminf(fmaxf(v + 3.0f, 0.0f), 6.0f) * (1.0f / 6.0f); // hswish
            yact[(size_t)b * (MIP * 128) + m * 128 + s] = v;
        }
    }
}

// ---------------------------------------------------------------------------
// Kernel 3: per-(b,c) gate-compute + apply.
//   gs[s] = sigmoid(sum_m W2[c][m] * yact[b][m][s])  (W2 = wh for s<64, ww else)
//   out[b,c,h,w] = x[b,c,h,w] * gs[h] * gs[64+w]
// ---------------------------------------------------------------------------
__global__ __launch_bounds__(256) void apply_kernel(const float* __restrict__ x,
                                                    const float* __restrict__ yact,
                                                    const float* __restrict__ wh,
                                                    const float* __restrict__ ww,
                                                    float* __restrict__ out) {
    const int bc = blockIdx.x;
    const int b  = bc >> 8;
    const int c  = bc & 255;
    const float* xp = x + (size_t)bc * (Hn * Wn);
    float* op = out + (size_t)bc * (Hn * Wn);

    __shared__ float gs[128];                        // [0,64): g_h, [64,128): g_w
    const int t = threadIdx.x;
    if (t < 128) {
        const float* w2row = (t < 64) ? (wh + c * MIP) : (ww + c * MIP); // wave-uniform
        const float* yb = yact + (size_t)b * (MIP * 128);
        float g = 0.f;
#pragma unroll
        for (int m = 0; m < MIP; ++m)
            g += w2row[m] * yb[m * 128 + t];         // coalesced over t
        gs[t] = 1.0f / (1.0f + expf(-g));
    }
    __syncthreads();

#pragma unroll
    for (int k = 0; k < 4; ++k) {
        int i4  = t + 256 * k;
        int idx = i4 * 4;
        int h = idx >> 6;
        int w = idx & 63;
        float4 v = ((const float4*)xp)[i4];
        float gh = gs[h];
        v.x *= gh * gs[64 + w + 0];
        v.y *= gh * gs[64 + w + 1];
        v.z *= gh * gs[64 + w + 2];
        v.w *= gh * gs[64 + w + 3];
        ((float4*)op)[i4] = v;
    }
}

extern "C" void kernel_launch(void* const* d_in, const int* in_sizes, int n_in,
                              void* d_out, int out_size, void* d_ws, size_t ws_size,
                              hipStream_t stream) {
    const float* x        = (const float*)d_in[0];
    const float* w1       = (const float*)d_in[1];
    const float* bn_gamma = (const float*)d_in[2];
    const float* bn_beta  = (const float*)d_in[3];
    const float* bn_mean  = (const float*)d_in[4];
    const float* bn_var   = (const float*)d_in[5];
    const float* wh       = (const float*)d_in[6];
    const float* ww       = (const float*)d_in[7];
    float* out = (float*)d_out;

    float* A    = (float*)d_ws;                            // Bn*Cn*128 floats = 4 MiB
    float* yact = A + (size_t)Bn * Cn * 128;               // Bn*MIP*128 floats = 128 KiB

    stats_kernel<<<Bn * Cn, 256, 0, stream>>>(x, A);
    ymix_kernel<<<Bn, 256, 0, stream>>>(A, w1, bn_gamma, bn_beta, bn_mean,
                                        bn_var, yact);
    apply_kernel<<<Bn * Cn, 256, 0, stream>>>(x, yact, wh, ww, out);
}

// Round 4
// 268.508 us; speedup vs baseline: 1.1567x; 1.1111x over previous
//
#include <hip/hip_runtime.h>
#include <math.h>

#define Bn 32
#define Cn 256
#define Hn 64
#define Wn 64
#define MIP 8
#define OUP 256
#define BN_EPS 1e-5f

typedef float vfloat4 __attribute__((ext_vector_type(4)));  // native vec for NT store

// ---------------------------------------------------------------------------
// Kernel 1: per-(b,c) stats -> A[b][c][s], s in [0,128)
//   s<64:  a_h[h] = rowsum[h]/64 + softmax_h(rowmax)[h]/64
//   s>=64: a_w[w] = colsum[w]/64 + softmax_w(colmax)[w]/64
// (uses: mean_W(bias_h*bias_w) = bias_h/64 since softmax sums to 1)
// ---------------------------------------------------------------------------
__global__ __launch_bounds__(256) void stats_kernel(const float* __restrict__ x,
                                                    float* __restrict__ A) {
    const int bc = blockIdx.x;                       // b*Cn + c
    const float* xp = x + (size_t)bc * (Hn * Wn);
    __shared__ float tile[Hn * 65];                  // pitch 65: 2-way alias max (free)
    const int t = threadIdx.x;

    // load 64x64 tile, float4-vectorized, coalesced (normal loads: WANT x in L3
    // for apply_kernel's re-read)
#pragma unroll
    for (int k = 0; k < 4; ++k) {
        int i4  = t + 256 * k;                       // float4 index 0..1023
        int idx = i4 * 4;
        int h = idx >> 6;
        int w = idx & 63;
        float4 v = ((const float4*)xp)[i4];
        float* dst = &tile[h * 65 + w];
        dst[0] = v.x; dst[1] = v.y; dst[2] = v.z; dst[3] = v.w;
    }
    __syncthreads();

    float red_max = -INFINITY, red_sum = 0.f;
    if (t < 64) {                                    // wave 0: row stats (fixed h)
        int h = t;
#pragma unroll 8
        for (int w = 0; w < Wn; ++w) {
            float v = tile[h * 65 + w];
            red_max = fmaxf(red_max, v);
            red_sum += v;
        }
    } else if (t < 128) {                            // wave 1: col stats (fixed w)
        int w = t - 64;
#pragma unroll 8
        for (int h = 0; h < Hn; ++h) {
            float v = tile[h * 65 + w];
            red_max = fmaxf(red_max, v);
            red_sum += v;
        }
    }

    if (t < 128) {
        // softmax across the 64 lanes of this wave
        float m = red_max;
#pragma unroll
        for (int off = 32; off > 0; off >>= 1) m = fmaxf(m, __shfl_xor(m, off));
        float e = __expf(red_max - m);
        float se = e;
#pragma unroll
        for (int off = 32; off > 0; off >>= 1) se += __shfl_xor(se, off);
        float a = (red_sum + e / se) * (1.0f / 64.0f);
        A[(size_t)bc * 128 + t] = a;
    }
}

// ---------------------------------------------------------------------------
// Kernel 2 (tiny): yact[b][m][s] = hswish(BN(sum_c w1[m][c] * A[b][c][s]))
//   1024 threads: s = t&127, K=256 split 8-way (32 c per thread), LDS combine.
// ---------------------------------------------------------------------------
__global__ __launch_bounds__(1024) void ymix_kernel(const float* __restrict__ A,
                                                    const float* __restrict__ w1,
                                                    const float* __restrict__ bn_gamma,
                                                    const float* __restrict__ bn_beta,
                                                    const float* __restrict__ bn_mean,
                                                    const float* __restrict__ bn_var,
                                                    float* __restrict__ yact) {
    const int b = blockIdx.x;
    const int t = threadIdx.x;
    const int s     = t & 127;
    const int chunk = t >> 7;                        // 0..7

    const float* Ab = A + (size_t)b * Cn * 128;

    float acc[MIP];
#pragma unroll
    for (int m = 0; m < MIP; ++m) acc[m] = 0.f;

    const int c0 = chunk * 32;
    for (int c = c0; c < c0 + 32; ++c) {
        float a = Ab[(size_t)c * 128 + s];           // coalesced over s
#pragma unroll
        for (int m = 0; m < MIP; ++m)
            acc[m] += w1[m * Cn + c] * a;            // wave-uniform scalar load
    }

    __shared__ float red[7][MIP][128];               // chunks 1..7
    if (chunk > 0) {
#pragma unroll
        for (int m = 0; m < MIP; ++m) red[chunk - 1][m][s] = acc[m];
    }
    __syncthreads();
    if (chunk == 0) {
#pragma unroll
        for (int m = 0; m < MIP; ++m) {
            float v = acc[m];
#pragma unroll
            for (int k = 0; k < 7; ++k) v += red[k][m][s];
            float sc = bn_gamma[m] * rsqrtf(bn_var[m] + BN_EPS);
            float sh = bn_beta[m] - bn_mean[m] * sc;
            v = v * sc + sh;
            v = v * fminf(fmaxf(v + 3.0f, 0.0f), 6.0f) * (1.0f / 6.0f); // hswish
            yact[(size_t)b * (MIP * 128) + m * 128 + s] = v;
        }
    }
}

// ---------------------------------------------------------------------------
// Kernel 3: per-(b,c) gate-compute + apply.
//   gs[s] = sigmoid(sum_m W2[c][m] * yact[b][m][s])  (W2 = wh for s<64, ww else)
//   out[b,c,h,w] = x[b,c,h,w] * gs[h] * gs[64+w]
//   Non-temporal out-stores: out is never re-read; keep x resident in L3.
// ---------------------------------------------------------------------------
__global__ __launch_bounds__(256) void apply_kernel(const float* __restrict__ x,
                                                    const float* __restrict__ yact,
                                                    const float* __restrict__ wh,
                                                    const float* __restrict__ ww,
                                                    float* __restrict__ out) {
    const int bc = blockIdx.x;
    const int b  = bc >> 8;
    const int c  = bc & 255;
    const float* xp = x + (size_t)bc * (Hn * Wn);
    float* op = out + (size_t)bc * (Hn * Wn);

    __shared__ float gs[128];                        // [0,64): g_h, [64,128): g_w
    const int t = threadIdx.x;
    if (t < 128) {
        const float* w2row = (t < 64) ? (wh + c * MIP) : (ww + c * MIP); // wave-uniform
        const float* yb = yact + (size_t)b * (MIP * 128);
        float g = 0.f;
#pragma unroll
        for (int m = 0; m < MIP; ++m)
            g += w2row[m] * yb[m * 128 + t];         // coalesced over t
        gs[t] = 1.0f / (1.0f + __expf(-g));
    }
    __syncthreads();

#pragma unroll
    for (int k = 0; k < 4; ++k) {
        int i4  = t + 256 * k;
        int idx = i4 * 4;
        int h = idx >> 6;
        int w = idx & 63;
        float4 v = ((const float4*)xp)[i4];
        float gh = gs[h];
        vfloat4 r;
        r.x = v.x * gh * gs[64 + w + 0];
        r.y = v.y * gh * gs[64 + w + 1];
        r.z = v.z * gh * gs[64 + w + 2];
        r.w = v.w * gh * gs[64 + w + 3];
        __builtin_nontemporal_store(r, &((vfloat4*)op)[i4]);
    }
}

extern "C" void kernel_launch(void* const* d_in, const int* in_sizes, int n_in,
                              void* d_out, int out_size, void* d_ws, size_t ws_size,
                              hipStream_t stream) {
    const float* x        = (const float*)d_in[0];
    const float* w1       = (const float*)d_in[1];
    const float* bn_gamma = (const float*)d_in[2];
    const float* bn_beta  = (const float*)d_in[3];
    const float* bn_mean  = (const float*)d_in[4];
    const float* bn_var   = (const float*)d_in[5];
    const float* wh       = (const float*)d_in[6];
    const float* ww       = (const float*)d_in[7];
    float* out = (float*)d_out;

    float* A    = (float*)d_ws;                            // Bn*Cn*128 floats = 4 MiB
    float* yact = A + (size_t)Bn * Cn * 128;               // Bn*MIP*128 floats = 128 KiB

    stats_kernel<<<Bn * Cn, 256, 0, stream>>>(x, A);
    ymix_kernel<<<Bn, 1024, 0, stream>>>(A, w1, bn_gamma, bn_beta, bn_mean,
                                         bn_var, yact);
    apply_kernel<<<Bn * Cn, 256, 0, stream>>>(x, yact, wh, ww, out);
}

// Round 5
// 267.709 us; speedup vs baseline: 1.1602x; 1.0030x over previous
//
#include <hip/hip_runtime.h>
#include <math.h>

#define Bn 32
#define Cn 256
#define Hn 64
#define Wn 64
#define MIP 8
#define OUP 256
#define BN_EPS 1e-5f

typedef float vfloat4 __attribute__((ext_vector_type(4)));  // native vec for NT ld/st

// ---------------------------------------------------------------------------
// Kernel 1: per-(b,c) stats -> A[b][c][s], s in [0,128)
//   s<64:  a_h[h] = (rowsum[h] + softmax_h(rowmax)[h]) / 64
//   s>=64: a_w[w] = (colsum[w] + softmax_w(colmax)[w]) / 64
// (uses: mean_W(bias_h*bias_w) = bias_h/64 since softmax_w sums to 1)
// All 4 waves participate in the reduction: waves 0/2 split each row's w-range,
// waves 1/3 split each column's h-range; partials combine via LDS.
// ---------------------------------------------------------------------------
__global__ __launch_bounds__(256) void stats_kernel(const float* __restrict__ x,
                                                    float* __restrict__ A) {
    const int bc = blockIdx.x;                       // b*Cn + c
    const float* xp = x + (size_t)bc * (Hn * Wn);
    __shared__ float tile[Hn * 65];                  // pitch 65: row & col conflict-free
    __shared__ float pmax[256], psum[256];
    const int t = threadIdx.x;

    // load 64x64 tile, float4-vectorized, coalesced (normal loads: WANT x in
    // L2/L3 for apply_kernel's re-read)
#pragma unroll
    for (int k = 0; k < 4; ++k) {
        int i4  = t + 256 * k;                       // float4 index 0..1023
        int idx = i4 * 4;
        int h = idx >> 6;
        int w = idx & 63;
        float4 v = ((const float4*)xp)[i4];
        float* dst = &tile[h * 65 + w];
        dst[0] = v.x; dst[1] = v.y; dst[2] = v.z; dst[3] = v.w;
    }
    __syncthreads();

    // half-range partial reductions (32 serial LDS reads each)
    {
        const int wv   = t >> 6;                     // wave id 0..3
        const int lane = t & 63;
        float m = -INFINITY, sm = 0.f;
        if ((wv & 1) == 0) {                         // waves 0,2: row lane, half (wv>>1)
            const int h = lane, w0 = (wv >> 1) * 32;
#pragma unroll 8
            for (int w = w0; w < w0 + 32; ++w) {
                float v = tile[h * 65 + w];
                m = fmaxf(m, v); sm += v;
            }
        } else {                                     // waves 1,3: col lane, half (wv>>1)
            const int w = lane, h0 = (wv >> 1) * 32;
#pragma unroll 8
            for (int h = h0; h < h0 + 32; ++h) {
                float v = tile[h * 65 + w];
                m = fmaxf(m, v); sm += v;
            }
        }
        pmax[t] = m; psum[t] = sm;
    }
    __syncthreads();

    if (t < 128) {
        float red_max = fmaxf(pmax[t], pmax[t + 128]);
        float red_sum = psum[t] + psum[t + 128];
        // softmax across the 64 lanes of this wave (wave0 = rows, wave1 = cols)
        float m = red_max;
#pragma unroll
        for (int off = 32; off > 0; off >>= 1) m = fmaxf(m, __shfl_xor(m, off));
        float e = __expf(red_max - m);
        float se = e;
#pragma unroll
        for (int off = 32; off > 0; off >>= 1) se += __shfl_xor(se, off);
        float a = (red_sum + e / se) * (1.0f / 64.0f);
        A[(size_t)bc * 128 + t] = a;
    }
}

// ---------------------------------------------------------------------------
// Kernel 2 (tiny): yact[b][m][s] = hswish(BN(sum_c w1[m][c] * A[b][c][s]))
//   1024 threads: s = t&127, K=256 split 8-way (32 c per thread), LDS combine.
// ---------------------------------------------------------------------------
__global__ __launch_bounds__(1024) void ymix_kernel(const float* __restrict__ A,
                                                    const float* __restrict__ w1,
                                                    const float* __restrict__ bn_gamma,
                                                    const float* __restrict__ bn_beta,
                                                    const float* __restrict__ bn_mean,
                                                    const float* __restrict__ bn_var,
                                                    float* __restrict__ yact) {
    const int b = blockIdx.x;
    const int t = threadIdx.x;
    const int s     = t & 127;
    const int chunk = t >> 7;                        // 0..7

    const float* Ab = A + (size_t)b * Cn * 128;

    float acc[MIP];
#pragma unroll
    for (int m = 0; m < MIP; ++m) acc[m] = 0.f;

    const int c0 = chunk * 32;
    for (int c = c0; c < c0 + 32; ++c) {
        float a = Ab[(size_t)c * 128 + s];           // coalesced over s
#pragma unroll
        for (int m = 0; m < MIP; ++m)
            acc[m] += w1[m * Cn + c] * a;            // wave-uniform scalar load
    }

    __shared__ float red[7][MIP][128];               // chunks 1..7
    if (chunk > 0) {
#pragma unroll
        for (int m = 0; m < MIP; ++m) red[chunk - 1][m][s] = acc[m];
    }
    __syncthreads();
    if (chunk == 0) {
#pragma unroll
        for (int m = 0; m < MIP; ++m) {
            float v = acc[m];
#pragma unroll
            for (int k = 0; k < 7; ++k) v += red[k][m][s];
            float sc = bn_gamma[m] * rsqrtf(bn_var[m] + BN_EPS);
            float sh = bn_beta[m] - bn_mean[m] * sc;
            v = v * sc + sh;
            v = v * fminf(fmaxf(v + 3.0f, 0.0f), 6.0f) * (1.0f / 6.0f); // hswish
            yact[(size_t)b * (MIP * 128) + m * 128 + s] = v;
        }
    }
}

// ---------------------------------------------------------------------------
// Kernel 3: per-(b,c) gate-compute + apply.
//   gs[s] = sigmoid(sum_m W2[c][m] * yact[b][m][s])  (W2 = wh for s<64, ww else)
//   out[b,c,h,w] = x[b,c,h,w] * gs[h] * gs[64+w]
//   NT loads for x (last use) + NT stores for out (never re-read).
// ---------------------------------------------------------------------------
__global__ __launch_bounds__(256) void apply_kernel(const float* __restrict__ x,
                                                    const float* __restrict__ yact,
                                                    const float* __restrict__ wh,
                                                    const float* __restrict__ ww,
                                                    float* __restrict__ out) {
    const int bc = blockIdx.x;
    const int b  = bc >> 8;
    const int c  = bc & 255;
    const float* xp = x + (size_t)bc * (Hn * Wn);
    float* op = out + (size_t)bc * (Hn * Wn);

    __shared__ float gs[128];                        // [0,64): g_h, [64,128): g_w
    const int t = threadIdx.x;
    if (t < 128) {
        const float* w2row = (t < 64) ? (wh + c * MIP) : (ww + c * MIP); // wave-uniform
        const float* yb = yact + (size_t)b * (MIP * 128);
        float g = 0.f;
#pragma unroll
        for (int m = 0; m < MIP; ++m)
            g += w2row[m] * yb[m * 128 + t];         // coalesced over t
        gs[t] = 1.0f / (1.0f + __expf(-g));
    }
    __syncthreads();

#pragma unroll
    for (int k = 0; k < 4; ++k) {
        int i4  = t + 256 * k;
        int idx = i4 * 4;
        int h = idx >> 6;
        int w = idx & 63;                            // w % 4 == 0 -> aligned b128
        vfloat4 v = __builtin_nontemporal_load(&((const vfloat4*)xp)[i4]);
        float gh = gs[h];
        float4 gw = *(const float4*)&gs[64 + w];     // one ds_read_b128
        vfloat4 r;
        r.x = v.x * gh * gw.x;
        r.y = v.y * gh * gw.y;
        r.z = v.z * gh * gw.z;
        r.w = v.w * gh * gw.w;
        __builtin_nontemporal_store(r, &((vfloat4*)op)[i4]);
    }
}

extern "C" void kernel_launch(void* const* d_in, const int* in_sizes, int n_in,
                              void* d_out, int out_size, void* d_ws, size_t ws_size,
                              hipStream_t stream) {
    const float* x        = (const float*)d_in[0];
    const float* w1       = (const float*)d_in[1];
    const float* bn_gamma = (const float*)d_in[2];
    const float* bn_beta  = (const float*)d_in[3];
    const float* bn_mean  = (const float*)d_in[4];
    const float* bn_var   = (const float*)d_in[5];
    const float* wh       = (const float*)d_in[6];
    const float* ww       = (const float*)d_in[7];
    float* out = (float*)d_out;

    float* A    = (float*)d_ws;                            // Bn*Cn*128 floats = 4 MiB
    float* yact = A + (size_t)Bn * Cn * 128;               // Bn*MIP*128 floats = 128 KiB

    stats_kernel<<<Bn * Cn, 256, 0, stream>>>(x, A);
    ymix_kernel<<<Bn, 1024, 0, stream>>>(A, w1, bn_gamma, bn_beta, bn_mean,
                                         bn_var, yact);
    apply_kernel<<<Bn * Cn, 256, 0, stream>>>(x, yact, wh, ww, out);
}